// Round 5
// baseline (982.128 us; speedup 1.0000x reference)
//
#include <hip/hip_runtime.h>
#include <hip/hip_bf16.h>

typedef __bf16 bf16;
typedef __attribute__((ext_vector_type(8))) __bf16 bf16x8;
typedef __attribute__((ext_vector_type(4))) float f32x4;

// Pack two f32x4 into a bf16x8 fragment (round-to-nearest via cast).
static __device__ inline bf16x8 pack_bf16x8(f32x4 lo, f32x4 hi) {
    bf16x8 t;
#pragma unroll
    for (int j = 0; j < 4; ++j) {
        t[j]     = (__bf16)lo[j];
        t[4 + j] = (__bf16)hi[j];
    }
    return t;
}

// ---------------------------------------------------------------------------
// Weight pre-conversion: fp32 W[128][128] -> bf16 fragments laid out so a
// sage wave's B-fragment load is ONE coalesced 16B bf16x8 load:
//   frag[mat][(ct*4+kc)*64 + q*16 + m] = W[ct*16+m][kc*32+q*8 .. +7]
// ---------------------------------------------------------------------------
struct WConvArgs { const float* w[10]; bf16* dst; };

__global__ __launch_bounds__(256)
void convert_w(WConvArgs A) {
    int mat = blockIdx.y;                       // 0..9 = (type*2 + {wl,wr})
    int tid = blockIdx.x * 256 + threadIdx.x;   // 0..2047
    if (tid >= 2048) return;
    int m  = tid & 15;
    int q  = (tid >> 4) & 3;
    int kc = (tid >> 6) & 3;
    int ct = tid >> 8;
    const float* src = A.w[mat] + (size_t)(ct * 16 + m) * 128 + kc * 32 + q * 8;
    bf16x8 t;
#pragma unroll
    for (int j = 0; j < 8; ++j) t[j] = (__bf16)src[j];
    bf16* dst = A.dst + (size_t)mat * 16384 + ((ct * 4 + kc) * 4 + q) * 128 + m * 8;
    *(bf16x8*)dst = t;
}

// ---------------------------------------------------------------------------
// Feature pre-conversion: fp32 x[n][128] -> bf16 (row-major). Gathers then
// read 256B rows: one 64B line per (kc) per row -> 4 line-requests per edge
// (the fp32 path costs 16). Same rounding as the previous in-kernel pack.
// ---------------------------------------------------------------------------
struct XConvArgs { const float* src[3]; bf16* dst[3]; long long n8[3]; };

__global__ __launch_bounds__(256)
void convert_x(XConvArgs A) {
    int a = blockIdx.y;
    const float* s = A.src[a];
    bf16* d = A.dst[a];
    long long n8 = A.n8[a];
    for (long long i = blockIdx.x * 256LL + threadIdx.x; i < n8;
         i += (long long)gridDim.x * 256) {
        const f32x4* p = (const f32x4*)(s + i * 8);
        ((bf16x8*)d)[i] = pack_bf16x8(p[0], p[1]);
    }
}

// ---------------------------------------------------------------------------
// CSR build (counting sort by destination), fused across up to 5 edge types
// via gridDim.y. All init by kernels (graph-capture safe); 4B atomics only.
// ---------------------------------------------------------------------------
struct CsrArgs {
    const int* si[5];
    const int* di[5];
    int* ofs[5];
    int* tick[5];
    int* esrc[5];
    int* bsum[5];
    int E[5];
    int n1[5];   // nd + 1
};

__global__ __launch_bounds__(256)
void csr_zero(CsrArgs A) {
    int t = blockIdx.y;
    int i = blockIdx.x * 256 + threadIdx.x;
    if (i < A.n1[t]) A.ofs[t][i] = 0;
}

__global__ __launch_bounds__(256)
void csr_hist(CsrArgs A) {
    int t = blockIdx.y;
    int E = A.E[t];
    const int* di = A.di[t];
    int* ofs = A.ofs[t];
    for (int i = blockIdx.x * 256 + threadIdx.x; i < E; i += gridDim.x * 256)
        atomicAdd(&ofs[di[i] + 1], 1);
}

// Inclusive scan, stage 1: per-block (2048 elems) scan + block totals.
__global__ __launch_bounds__(256)
void csr_scan_blocks(CsrArgs A) {
    __shared__ int lds[256];
    int ty = blockIdx.y;
    int n = A.n1[ty];
    int* a = A.ofs[ty];
    int* bsum = A.bsum[ty];
    int t = threadIdx.x;
    int base = blockIdx.x * 2048 + t * 8;
    int v[8];
    int run = 0;
#pragma unroll
    for (int j = 0; j < 8; ++j) {
        int idx = base + j;
        int x = (idx < n) ? a[idx] : 0;
        run += x;
        v[j] = run;
    }
    lds[t] = run;
    __syncthreads();
#pragma unroll
    for (int off = 1; off < 256; off <<= 1) {
        int x = (t >= off) ? lds[t - off] : 0;
        __syncthreads();
        lds[t] += x;
        __syncthreads();
    }
    int excl = t ? lds[t - 1] : 0;
#pragma unroll
    for (int j = 0; j < 8; ++j) {
        int idx = base + j;
        if (idx < n) a[idx] = v[j] + excl;
    }
    if (t == 255) bsum[blockIdx.x] = lds[255];
}

// Stage 2: exclusive scan of block totals (one block per type).
__global__ __launch_bounds__(256)
void csr_scan_bsums(CsrArgs A, int nb) {
    __shared__ int lds[256];
    int ty = blockIdx.x;
    int* bsum = A.bsum[ty];
    int t = threadIdx.x;
    int carry = 0;
    for (int base = 0; base < nb; base += 256) {
        int i = base + t;
        int v = (i < nb) ? bsum[i] : 0;
        lds[t] = v;
        __syncthreads();
#pragma unroll
        for (int off = 1; off < 256; off <<= 1) {
            int x = (t >= off) ? lds[t - off] : 0;
            __syncthreads();
            lds[t] += x;
            __syncthreads();
        }
        int excl = t ? lds[t - 1] : 0;
        if (i < nb) bsum[i] = excl + carry;
        carry += lds[255];
        __syncthreads();
    }
}

// Stage 3: add block offsets; init per-row tickets tick[d] = start(d).
__global__ __launch_bounds__(256)
void csr_scan_add(CsrArgs A) {
    int ty = blockIdx.y;
    int n = A.n1[ty];
    int* a = A.ofs[ty];
    const int* bsum = A.bsum[ty];
    int* tick = A.tick[ty];
    int i = blockIdx.x * 256 + threadIdx.x;
    if (i < n) {
        int v = a[i] + bsum[i >> 11];
        a[i] = v;
        if (i < n - 1) tick[i] = v;
    }
}

// Ticketed bucket fill: esrc[slot] = source id, grouped by destination.
// pos clamped: no state (even corrupt) can cause an OOB write.
__global__ __launch_bounds__(256)
void csr_fill(CsrArgs A) {
    int ty = blockIdx.y;
    int E = A.E[ty];
    const int* si = A.si[ty];
    const int* di = A.di[ty];
    int* tick = A.tick[ty];
    int* esrc = A.esrc[ty];
    for (int i = blockIdx.x * 256 + threadIdx.x; i < E; i += gridDim.x * 256) {
        int pos = atomicAdd(&tick[di[i]], 1);
        pos = pos < 0 ? 0 : (pos >= E ? E - 1 : pos);  // healthy path: no-op
        esrc[pos] = si[i];
    }
}

// ---------------------------------------------------------------------------
// Fully fused SAGE: one launch covers all destination groups (block-range
// partition). Per group, per contribution c:
//   y_c = x_dst@WLc^T + b_c + mean_{e in CSRc row}(x_srcc[e])@WRc^T
// out_row = sum_c L2norm(y_c). Wave = 16 rows x 128 cols, 8 col-tiles of
// mfma_f32_16x16x32_bf16. BF16S=1: sources/x_dst read as pre-converted bf16
// fragments (1 coalesced 64B line per kc per row). All CSR indices clamped.
// ---------------------------------------------------------------------------
struct SageAll {
    int bend[3];            // exclusive cumulative block counts
    int nd[3];
    int nc[3];
    const float* xdst_f[3];
    const bf16*  xdst_b[3];
    float* out[3];
    const float* xsrc_f[3][2];
    const bf16*  xsrc_b[3][2];
    const int* ofs[3][2];
    const int* esrc[3][2];
    const bf16* wf[3][2];
    const float* bias[3][2];
    int nsrc[3][2];
    int E[3][2];
};

template<int BF16S>
__global__ __launch_bounds__(256)
void sage_all(SageAll A) {
    int bid = blockIdx.x;
    int g = (bid >= A.bend[0]) + (bid >= A.bend[1]);
    int bloc = bid - (g ? A.bend[g - 1] : 0);
    int lane = threadIdx.x & 63;
    int wave = threadIdx.x >> 6;
    int m = lane & 15;   // A row within tile / C col within tile
    int q = lane >> 4;   // quad
    int nd = A.nd[g];
    int r0 = bloc * 64 + wave * 16;
    int rl = min(r0 + m, nd - 1);

    // A1 fragments: x_dst row rl. bf16 path: direct 16B fragment loads.
    bf16x8 a1[4];
    if constexpr (BF16S) {
        const bf16x8* xr = (const bf16x8*)(A.xdst_b[g] + (size_t)rl * 128);
#pragma unroll
        for (int kc = 0; kc < 4; ++kc) a1[kc] = xr[kc * 4 + q];
    } else {
        const f32x4* xrow = (const f32x4*)(A.xdst_f[g] + (size_t)rl * 128);
#pragma unroll
        for (int kc = 0; kc < 4; ++kc)
            a1[kc] = pack_bf16x8(xrow[kc * 8 + q * 2], xrow[kc * 8 + q * 2 + 1]);
    }

    float ysum[8][4];
#pragma unroll
    for (int ct = 0; ct < 8; ++ct)
#pragma unroll
        for (int r = 0; r < 4; ++r) ysum[ct][r] = 0.f;

    int nc = A.nc[g];
    for (int c = 0; c < nc; ++c) {
        const int* ofs  = A.ofs[g][c];
        const int* esrc = A.esrc[g][c];
        int nsrc = A.nsrc[g][c];
        int Et   = A.E[g][c];

        int start = ofs[rl];
        int end   = ofs[rl + 1];
        start = start < 0 ? 0 : (start > Et ? Et : start);
        end   = end < start ? start : (end > Et ? Et : end);

        f32x4 aglo[4], aghi[4];
#pragma unroll
        for (int kc = 0; kc < 4; ++kc) {
            aglo[kc] = (f32x4){0.f, 0.f, 0.f, 0.f};
            aghi[kc] = (f32x4){0.f, 0.f, 0.f, 0.f};
        }

        int e = start;
        if constexpr (BF16S) {
            const bf16* xs = A.xsrc_b[g][c];
            for (; e + 2 <= end; e += 2) {
                int s0 = esrc[e], s1 = esrc[e + 1];
                s0 = s0 < 0 ? 0 : (s0 >= nsrc ? nsrc - 1 : s0);
                s1 = s1 < 0 ? 0 : (s1 >= nsrc ? nsrc - 1 : s1);
                const bf16x8* p0 = (const bf16x8*)(xs + (size_t)s0 * 128);
                const bf16x8* p1 = (const bf16x8*)(xs + (size_t)s1 * 128);
#pragma unroll
                for (int kc = 0; kc < 4; ++kc) {
                    bf16x8 v0 = p0[kc * 4 + q];
                    bf16x8 v1 = p1[kc * 4 + q];
#pragma unroll
                    for (int j = 0; j < 4; ++j) {
                        aglo[kc][j] += (float)v0[j] + (float)v1[j];
                        aghi[kc][j] += (float)v0[4 + j] + (float)v1[4 + j];
                    }
                }
            }
            if (e < end) {
                int s0 = esrc[e];
                s0 = s0 < 0 ? 0 : (s0 >= nsrc ? nsrc - 1 : s0);
                const bf16x8* p0 = (const bf16x8*)(xs + (size_t)s0 * 128);
#pragma unroll
                for (int kc = 0; kc < 4; ++kc) {
                    bf16x8 v0 = p0[kc * 4 + q];
#pragma unroll
                    for (int j = 0; j < 4; ++j) {
                        aglo[kc][j] += (float)v0[j];
                        aghi[kc][j] += (float)v0[4 + j];
                    }
                }
            }
        } else {
            const float* xs = A.xsrc_f[g][c];
            for (; e + 2 <= end; e += 2) {
                int s0 = esrc[e], s1 = esrc[e + 1];
                s0 = s0 < 0 ? 0 : (s0 >= nsrc ? nsrc - 1 : s0);
                s1 = s1 < 0 ? 0 : (s1 >= nsrc ? nsrc - 1 : s1);
                const f32x4* p0 = (const f32x4*)(xs + (size_t)s0 * 128 + q * 8);
                const f32x4* p1 = (const f32x4*)(xs + (size_t)s1 * 128 + q * 8);
#pragma unroll
                for (int kc = 0; kc < 4; ++kc) {
                    aglo[kc] += p0[kc * 8] + p1[kc * 8];
                    aghi[kc] += p0[kc * 8 + 1] + p1[kc * 8 + 1];
                }
            }
            if (e < end) {
                int s0 = esrc[e];
                s0 = s0 < 0 ? 0 : (s0 >= nsrc ? nsrc - 1 : s0);
                const f32x4* p0 = (const f32x4*)(xs + (size_t)s0 * 128 + q * 8);
#pragma unroll
                for (int kc = 0; kc < 4; ++kc) {
                    aglo[kc] += p0[kc * 8];
                    aghi[kc] += p0[kc * 8 + 1];
                }
            }
        }

        float invc = 1.0f / (float)max(end - start, 1);
        bf16x8 a2[4];
#pragma unroll
        for (int kc = 0; kc < 4; ++kc) {
            bf16x8 t;
#pragma unroll
            for (int j = 0; j < 4; ++j) {
                t[j]     = (__bf16)(aglo[kc][j] * invc);
                t[4 + j] = (__bf16)(aghi[kc][j] * invc);
            }
            a2[kc] = t;
        }

        // 8 col-tiles; B fragments are direct 16B bf16x8 loads (L2-resident).
        const bf16x8* wf = (const bf16x8*)A.wf[g][c];
        int fb = q * 16 + m;
        f32x4 acc[8];
#pragma unroll
        for (int ct = 0; ct < 8; ++ct) {
            f32x4 cc = {0.f, 0.f, 0.f, 0.f};
#pragma unroll
            for (int kc = 0; kc < 4; ++kc) {
                bf16x8 bl = wf[(ct * 4 + kc) * 64 + fb];
                bf16x8 br = wf[2048 + (ct * 4 + kc) * 64 + fb];
                cc = __builtin_amdgcn_mfma_f32_16x16x32_bf16(a1[kc], bl, cc, 0, 0, 0);
                cc = __builtin_amdgcn_mfma_f32_16x16x32_bf16(a2[kc], br, cc, 0, 0, 0);
            }
            acc[ct] = cc;
        }

        // +bias, per-row L2 norm, accumulate normalized result in registers.
        const float* bias = A.bias[g][c];
        float ss[4] = {0.f, 0.f, 0.f, 0.f};
#pragma unroll
        for (int ct = 0; ct < 8; ++ct) {
            float bb = bias[ct * 16 + m];
#pragma unroll
            for (int r = 0; r < 4; ++r) {
                float v = acc[ct][r] + bb;
                acc[ct][r] = v;
                ss[r] += v * v;
            }
        }
#pragma unroll
        for (int off = 1; off < 16; off <<= 1) {
#pragma unroll
            for (int r = 0; r < 4; ++r) ss[r] += __shfl_xor(ss[r], off);
        }
        float sc[4];
#pragma unroll
        for (int r = 0; r < 4; ++r) sc[r] = 1.0f / fmaxf(sqrtf(ss[r]), 1e-12f);
#pragma unroll
        for (int ct = 0; ct < 8; ++ct)
#pragma unroll
            for (int r = 0; r < 4; ++r) ysum[ct][r] += acc[ct][r] * sc[r];
    }

    // Single store pass (no read-modify-write of global output).
#pragma unroll
    for (int r = 0; r < 4; ++r) {
        int orow = r0 + q * 4 + r;  // C/D: row = quad*4 + reg
        if (orow < nd) {
            float* op = A.out[g] + (size_t)orow * 128 + m;
#pragma unroll
            for (int ct = 0; ct < 8; ++ct) op[ct * 16] = ysum[ct][r];
        }
    }
}

extern "C" void kernel_launch(void* const* d_in, const int* in_sizes, int n_in,
                              void* d_out, int out_size, void* d_ws, size_t ws_size,
                              hipStream_t stream) {
    const int D = 128;
    const float* xarr[3] = {(const float*)d_in[0], (const float*)d_in[1],
                            (const float*)d_in[2]};
    int NA = in_sizes[0] / D;
    int NE = in_sizes[1] / D;
    int NF = in_sizes[2] / D;
    int nrow[3] = {NA, NE, NF};

    const int* si[5];
    const int* di[5];
    int Et[5];
    for (int i = 0; i < 5; ++i) {
        si[i] = (const int*)d_in[3 + 2 * i];
        di[i] = (const int*)d_in[4 + 2 * i];
        Et[i] = in_sizes[3 + 2 * i];
    }
    const float *wl[5], *bia[5], *wr[5];
    for (int i = 0; i < 5; ++i) {
        wl[i]  = (const float*)d_in[13 + 3 * i];
        bia[i] = (const float*)d_in[14 + 3 * i];
        wr[i]  = (const float*)d_in[15 + 3 * i];
    }

    float* outp = (float*)d_out;
    float* grp_out[3] = {outp, outp + (size_t)NA * D, outp + (size_t)(NA + NE) * D};

    // EDGE_TYPES: (art->ent), (art->fact), (ent->art), (ent->fact), (fact->ent)
    int xsrc_idx[5] = {0, 0, 1, 1, 2};
    int ndst[5]     = {NE, NF, NA, NF, NE};
    int grp_types[3][2] = {{2, -1}, {0, 4}, {1, 3}};  // article, entity, fact
    int grp_nt[3]  = {1, 2, 2};
    int grp_nd[3]  = {NA, NE, NF};
    int grp_dst[3] = {0, 1, 2};

    // ---------- workspace layout / mode selection ----------
    size_t wf_bytes = (size_t)5 * 32768 * sizeof(bf16);
    size_t csr_all_ints = 0;
    for (int t = 0; t < 5; ++t)
        csr_all_ints += (size_t)(ndst[t] + 1) + ndst[t] + Et[t] + 128;
    size_t xb_elems = ((size_t)NA + NE + NF) * D;

    size_t off_csr = (wf_bytes + 15) & ~(size_t)15;
    size_t off_xb  = (off_csr + csr_all_ints * 4 + 15) & ~(size_t)15;
    int mode_full = (off_xb + xb_elems * sizeof(bf16)) <= ws_size;
    int mode_lean = (off_csr + csr_all_ints * 4) <= ws_size;

    bf16* wfrag = (bf16*)d_ws;
    WConvArgs wa;
    for (int t = 0; t < 5; ++t) {
        wa.w[t * 2]     = wl[t];
        wa.w[t * 2 + 1] = wr[t];
    }
    wa.dst = wfrag;
    convert_w<<<dim3(8, 10), 256, 0, stream>>>(wa);

    bf16* xb = (bf16*)((char*)d_ws + off_xb);
    bf16* xb_arr[3] = {xb, xb + (size_t)NA * D, xb + ((size_t)NA + NE) * D};
    if (mode_full) {
        XConvArgs xa;
        for (int a = 0; a < 3; ++a) {
            xa.src[a] = xarr[a];
            xa.dst[a] = xb_arr[a];
            xa.n8[a]  = (long long)nrow[a] * 16;
        }
        convert_x<<<dim3(2048, 3), 256, 0, stream>>>(xa);
    }

    // CSR pipeline helper over a list of types laid out from `base`.
    int* type_ofs[5];
    int* type_esrc[5];
    auto run_csr = [&](const int* types, int nt, int* base) {
        CsrArgs ca = {};
        int* p = base;
        int max_n1 = 0;
        for (int k = 0; k < nt; ++k) {
            int t = types[k];
            int nd = ndst[t], n1 = nd + 1, E = Et[t];
            ca.si[k] = si[t];
            ca.di[k] = di[t];
            ca.ofs[k]  = p; p += n1;
            ca.tick[k] = p; p += nd;
            ca.esrc[k] = p; p += E;
            ca.bsum[k] = p; p += 128;
            ca.E[k] = E;
            ca.n1[k] = n1;
            if (n1 > max_n1) max_n1 = n1;
            type_ofs[t]  = ca.ofs[k];
            type_esrc[t] = ca.esrc[k];
        }
        int blk = (max_n1 + 255) / 256;
        int nb  = (max_n1 + 2047) / 2048;
        csr_zero<<<dim3(blk, nt), 256, 0, stream>>>(ca);
        csr_hist<<<dim3(1024, nt), 256, 0, stream>>>(ca);
        csr_scan_blocks<<<dim3(nb, nt), 256, 0, stream>>>(ca);
        csr_scan_bsums<<<dim3(nt), 256, 0, stream>>>(ca, nb);
        csr_scan_add<<<dim3(blk, nt), 256, 0, stream>>>(ca);
        csr_fill<<<dim3(1024, nt), 256, 0, stream>>>(ca);
    };

    auto fill_group = [&](SageAll& sa, int slot, int g) {
        sa.nd[slot] = grp_nd[g];
        sa.nc[slot] = grp_nt[g];
        sa.xdst_f[slot] = xarr[grp_dst[g]];
        sa.xdst_b[slot] = xb_arr[grp_dst[g]];
        sa.out[slot] = grp_out[g];
        for (int c = 0; c < grp_nt[g]; ++c) {
            int t = grp_types[g][c];
            sa.xsrc_f[slot][c] = xarr[xsrc_idx[t]];
            sa.xsrc_b[slot][c] = xb_arr[xsrc_idx[t]];
            sa.ofs[slot][c]  = type_ofs[t];
            sa.esrc[slot][c] = type_esrc[t];
            sa.wf[slot][c]   = wfrag + (size_t)t * 32768;
            sa.bias[slot][c] = bia[t];
            sa.nsrc[slot][c] = nrow[xsrc_idx[t]];
            sa.E[slot][c]    = Et[t];
        }
    };

    int* csr_base = (int*)((char*)d_ws + off_csr);

    if (mode_lean) {
        // All 5 CSRs in one fused pipeline, then one fused sage launch.
        int all_types[5] = {0, 1, 2, 3, 4};
        run_csr(all_types, 5, csr_base);

        SageAll sa = {};
        int cum = 0;
        for (int g = 0; g < 3; ++g) {
            fill_group(sa, g, g);
            cum += (grp_nd[g] + 63) / 64;
            sa.bend[g] = cum;
        }
        if (mode_full)
            sage_all<1><<<cum, 256, 0, stream>>>(sa);
        else
            sage_all<0><<<cum, 256, 0, stream>>>(sa);
    } else {
        // Minimal-workspace fallback: per-group CSR + sage (round-3 behavior).
        for (int g = 0; g < 3; ++g) {
            run_csr(grp_types[g], grp_nt[g], csr_base);
            SageAll sa = {};
            fill_group(sa, 0, g);
            int nb = (grp_nd[g] + 63) / 64;
            sa.bend[0] = nb; sa.bend[1] = nb; sa.bend[2] = nb;
            sage_all<0><<<nb, 256, 0, stream>>>(sa);
        }
    }
}

// Round 6
// 857.660 us; speedup vs baseline: 1.1451x; 1.1451x over previous
//
#include <hip/hip_runtime.h>
#include <hip/hip_bf16.h>

typedef __bf16 bf16;
typedef __attribute__((ext_vector_type(8))) __bf16 bf16x8;
typedef __attribute__((ext_vector_type(4))) float f32x4;

// Pack two f32x4 into a bf16x8 fragment (round-to-nearest via cast).
static __device__ inline bf16x8 pack_bf16x8(f32x4 lo, f32x4 hi) {
    bf16x8 t;
#pragma unroll
    for (int j = 0; j < 4; ++j) {
        t[j]     = (__bf16)lo[j];
        t[4 + j] = (__bf16)hi[j];
    }
    return t;
}

// ---------------------------------------------------------------------------
// Weight pre-conversion: fp32 W[128][128] -> bf16 fragments laid out so a
// sage wave's B-fragment load is ONE coalesced 16B bf16x8 load.
// ---------------------------------------------------------------------------
struct WConvArgs { const float* w[10]; bf16* dst; };

__global__ __launch_bounds__(256)
void convert_w(WConvArgs A) {
    int mat = blockIdx.y;                       // 0..9 = (type*2 + {wl,wr})
    int tid = blockIdx.x * 256 + threadIdx.x;   // 0..2047
    if (tid >= 2048) return;
    int m  = tid & 15;
    int q  = (tid >> 4) & 3;
    int kc = (tid >> 6) & 3;
    int ct = tid >> 8;
    const float* src = A.w[mat] + (size_t)(ct * 16 + m) * 128 + kc * 32 + q * 8;
    bf16x8 t;
#pragma unroll
    for (int j = 0; j < 8; ++j) t[j] = (__bf16)src[j];
    bf16* dst = A.dst + (size_t)mat * 16384 + ((ct * 4 + kc) * 4 + q) * 128 + m * 8;
    *(bf16x8*)dst = t;
}

// ---------------------------------------------------------------------------
// Feature pre-conversion: fp32 x[n][128] -> bf16 row-major (gathers then
// read 256B rows -> 4 line-requests per edge instead of 16).
// ---------------------------------------------------------------------------
struct XConvArgs { const float* src[3]; bf16* dst[3]; long long n8[3]; };

__global__ __launch_bounds__(256)
void convert_x(XConvArgs A) {
    int a = blockIdx.y;
    const float* s = A.src[a];
    bf16* d = A.dst[a];
    long long n8 = A.n8[a];
    for (long long i = blockIdx.x * 256LL + threadIdx.x; i < n8;
         i += (long long)gridDim.x * 256) {
        const f32x4* p = (const f32x4*)(s + i * 8);
        ((bf16x8*)d)[i] = pack_bf16x8(p[0], p[1]);
    }
}

// ---------------------------------------------------------------------------
// PATH A: fixed-capacity bucket grouping. ONE atomic per edge (vs CSR's two
// plus scan). bucket[d*C + t] = src for the first C edges of d; the rest go
// to an exact per-type overflow list (capacity E -> no input loses edges).
// All init by kernels (graph-capture safe).
// ---------------------------------------------------------------------------
struct FillArgs {
    const int* si[5];
    const int* di[5];
    int* tick[5];      // per-dst running count (final = degree)
    int* bucket[5];    // [nd * C]
    int2* ovf[5];      // overflow (dst, src) pairs
    int* ovfn[5];      // overflow counts
    int E[5];
    int nd[5];
    int C;
};

__global__ __launch_bounds__(256)
void bkt_zero(FillArgs A) {
    int t = blockIdx.y;
    int nd = A.nd[t];
    int* tick = A.tick[t];
    for (int i = blockIdx.x * 256 + threadIdx.x; i < nd; i += gridDim.x * 256)
        tick[i] = 0;
    if (blockIdx.x == 0 && threadIdx.x == 0) *A.ovfn[t] = 0;
}

__global__ __launch_bounds__(256)
void bkt_fill(FillArgs A) {
    int t = blockIdx.y;
    int E = A.E[t];
    int nd = A.nd[t];
    int C = A.C;
    const int* si = A.si[t];
    const int* di = A.di[t];
    int* tick = A.tick[t];
    int* bucket = A.bucket[t];
    int2* ovf = A.ovf[t];
    int* ovfn = A.ovfn[t];
    for (int i = blockIdx.x * 256 + threadIdx.x; i < E; i += gridDim.x * 256) {
        int d = di[i];
        int s = si[i];
        d = d < 0 ? 0 : (d >= nd ? nd - 1 : d);  // healthy path: no-op
        int pos = atomicAdd(&tick[d], 1);
        if (pos >= 0 && pos < C) {
            bucket[(size_t)d * C + pos] = s;
        } else {
            int o = atomicAdd(ovfn, 1);
            if (o >= 0 && o < E) ovf[o] = make_int2(d, s);  // o<E always healthy
        }
    }
}

// Accumulate one gathered source row into the lane's 32-col fragment slice.
template<int BF16S>
static __device__ inline void accum_src(const float* xf, const bf16* xb,
                                        int s, int q, f32x4* aglo, f32x4* aghi) {
    if constexpr (BF16S) {
        const bf16x8* p = (const bf16x8*)(xb + (size_t)s * 128);
#pragma unroll
        for (int kc = 0; kc < 4; ++kc) {
            bf16x8 v = p[kc * 4 + q];
#pragma unroll
            for (int j = 0; j < 4; ++j) {
                aglo[kc][j] += (float)v[j];
                aghi[kc][j] += (float)v[4 + j];
            }
        }
    } else {
        const f32x4* p = (const f32x4*)(xf + (size_t)s * 128 + q * 8);
#pragma unroll
        for (int kc = 0; kc < 4; ++kc) {
            aglo[kc] += p[kc * 8];
            aghi[kc] += p[kc * 8 + 1];
        }
    }
}

// ---------------------------------------------------------------------------
// Fully fused SAGE over bucket-grouped edges. One launch, 3 destination
// groups (block-range partition). Per contribution:
//   y_c = x_dst@WLc^T + b_c + mean_{bucket row + ovf}(x_srcc)@WRc^T
// out_row = sum_c L2norm(y_c). Wave = 16 rows x 128 cols, 8 col-tiles of
// mfma_f32_16x16x32_bf16. Bucket rows are contiguous -> int4 src-id loads.
// ---------------------------------------------------------------------------
struct SageB {
    int bend[3];
    int nd[3];
    int nc[3];
    const float* xdst_f[3];
    const bf16*  xdst_b[3];
    float* out[3];
    const float* xsrc_f[3][2];
    const bf16*  xsrc_b[3][2];
    const int* tick[3][2];
    const int* bucket[3][2];
    const int2* ovf[3][2];
    const int* ovfn[3][2];
    const bf16* wf[3][2];
    const float* bias[3][2];
    int nsrc[3][2];
    int ovfcap[3][2];
};

template<int C, int BF16S>
__global__ __launch_bounds__(256)
void sage_bkt(SageB A) {
    int bid = blockIdx.x;
    int g = (bid >= A.bend[0]) + (bid >= A.bend[1]);
    int bloc = bid - (g ? A.bend[g - 1] : 0);
    int lane = threadIdx.x & 63;
    int wave = threadIdx.x >> 6;
    int m = lane & 15;
    int q = lane >> 4;
    int nd = A.nd[g];
    int r0 = bloc * 64 + wave * 16;
    int rl = min(r0 + m, nd - 1);

    // A1 fragments: x_dst row rl.
    bf16x8 a1[4];
    if constexpr (BF16S) {
        const bf16x8* xr = (const bf16x8*)(A.xdst_b[g] + (size_t)rl * 128);
#pragma unroll
        for (int kc = 0; kc < 4; ++kc) a1[kc] = xr[kc * 4 + q];
    } else {
        const f32x4* xrow = (const f32x4*)(A.xdst_f[g] + (size_t)rl * 128);
#pragma unroll
        for (int kc = 0; kc < 4; ++kc)
            a1[kc] = pack_bf16x8(xrow[kc * 8 + q * 2], xrow[kc * 8 + q * 2 + 1]);
    }

    float ysum[8][4];
#pragma unroll
    for (int ct = 0; ct < 8; ++ct)
#pragma unroll
        for (int r = 0; r < 4; ++r) ysum[ct][r] = 0.f;

    int nc = A.nc[g];
    for (int c = 0; c < nc; ++c) {
        const float* xf = A.xsrc_f[g][c];
        const bf16*  xb = A.xsrc_b[g][c];
        int nsrc = A.nsrc[g][c];

        int deg = A.tick[g][c][rl];
        deg = deg < 0 ? 0 : deg;
        int dc = deg < C ? deg : C;
        const int* brow = A.bucket[g][c] + (size_t)rl * C;

        f32x4 aglo[4], aghi[4];
#pragma unroll
        for (int kc = 0; kc < 4; ++kc) {
            aglo[kc] = (f32x4){0.f, 0.f, 0.f, 0.f};
            aghi[kc] = (f32x4){0.f, 0.f, 0.f, 0.f};
        }

        // Contiguous bucket row: int4 id loads, chunk of 4 gathers in flight.
#pragma unroll
        for (int t0 = 0; t0 < C; t0 += 4) {
            if (t0 < dc) {
                int4 s4 = *(const int4*)(brow + t0);
                int ss[4] = {s4.x, s4.y, s4.z, s4.w};
#pragma unroll
                for (int u = 0; u < 4; ++u) {
                    if (t0 + u < dc) {
                        int s = ss[u];
                        s = s < 0 ? 0 : (s >= nsrc ? nsrc - 1 : s);
                        accum_src<BF16S>(xf, xb, s, q, aglo, aghi);
                    }
                }
            }
        }
        // Rare exact overflow path (deg > C): scan tiny per-type list.
        if (deg > C) {
            int on = *A.ovfn[g][c];
            int cap = A.ovfcap[g][c];
            on = on < 0 ? 0 : (on > cap ? cap : on);
            const int2* ov = A.ovf[g][c];
            for (int i = 0; i < on; ++i) {
                int2 ds = ov[i];
                if (ds.x == rl) {
                    int s = ds.y;
                    s = s < 0 ? 0 : (s >= nsrc ? nsrc - 1 : s);
                    accum_src<BF16S>(xf, xb, s, q, aglo, aghi);
                }
            }
        }

        float invc = 1.0f / (float)(deg > 0 ? deg : 1);
        bf16x8 a2[4];
#pragma unroll
        for (int kc = 0; kc < 4; ++kc) {
            bf16x8 t;
#pragma unroll
            for (int j = 0; j < 4; ++j) {
                t[j]     = (__bf16)(aglo[kc][j] * invc);
                t[4 + j] = (__bf16)(aghi[kc][j] * invc);
            }
            a2[kc] = t;
        }

        // 8 col-tiles; B fragments are direct 16B bf16x8 loads (L2-resident).
        const bf16x8* wf = (const bf16x8*)A.wf[g][c];
        int fb = q * 16 + m;
        f32x4 acc[8];
#pragma unroll
        for (int ct = 0; ct < 8; ++ct) {
            f32x4 cc = {0.f, 0.f, 0.f, 0.f};
#pragma unroll
            for (int kc = 0; kc < 4; ++kc) {
                bf16x8 bl = wf[(ct * 4 + kc) * 64 + fb];
                bf16x8 br = wf[2048 + (ct * 4 + kc) * 64 + fb];
                cc = __builtin_amdgcn_mfma_f32_16x16x32_bf16(a1[kc], bl, cc, 0, 0, 0);
                cc = __builtin_amdgcn_mfma_f32_16x16x32_bf16(a2[kc], br, cc, 0, 0, 0);
            }
            acc[ct] = cc;
        }

        // +bias, per-row L2 norm, accumulate normalized result in registers.
        const float* bias = A.bias[g][c];
        float ss2[4] = {0.f, 0.f, 0.f, 0.f};
#pragma unroll
        for (int ct = 0; ct < 8; ++ct) {
            float bb = bias[ct * 16 + m];
#pragma unroll
            for (int r = 0; r < 4; ++r) {
                float v = acc[ct][r] + bb;
                acc[ct][r] = v;
                ss2[r] += v * v;
            }
        }
#pragma unroll
        for (int off = 1; off < 16; off <<= 1) {
#pragma unroll
            for (int r = 0; r < 4; ++r) ss2[r] += __shfl_xor(ss2[r], off);
        }
        float sc[4];
#pragma unroll
        for (int r = 0; r < 4; ++r) sc[r] = 1.0f / fmaxf(sqrtf(ss2[r]), 1e-12f);
#pragma unroll
        for (int ct = 0; ct < 8; ++ct)
#pragma unroll
            for (int r = 0; r < 4; ++r) ysum[ct][r] += acc[ct][r] * sc[r];
    }

#pragma unroll
    for (int r = 0; r < 4; ++r) {
        int orow = r0 + q * 4 + r;
        if (orow < nd) {
            float* op = A.out[g] + (size_t)orow * 128 + m;
#pragma unroll
            for (int ct = 0; ct < 8; ++ct) op[ct * 16] = ysum[ct][r];
        }
    }
}

// ---------------------------------------------------------------------------
// PATH B (fallback, proven): round-5 CSR build + sage_all. Used only when the
// bucket layout does not fit ws_size.
// ---------------------------------------------------------------------------
struct CsrArgs {
    const int* si[5];
    const int* di[5];
    int* ofs[5];
    int* tick[5];
    int* esrc[5];
    int* bsum[5];
    int E[5];
    int n1[5];
};

__global__ __launch_bounds__(256)
void csr_zero(CsrArgs A) {
    int t = blockIdx.y;
    int i = blockIdx.x * 256 + threadIdx.x;
    if (i < A.n1[t]) A.ofs[t][i] = 0;
}

__global__ __launch_bounds__(256)
void csr_hist(CsrArgs A) {
    int t = blockIdx.y;
    int E = A.E[t];
    const int* di = A.di[t];
    int* ofs = A.ofs[t];
    for (int i = blockIdx.x * 256 + threadIdx.x; i < E; i += gridDim.x * 256)
        atomicAdd(&ofs[di[i] + 1], 1);
}

__global__ __launch_bounds__(256)
void csr_scan_blocks(CsrArgs A) {
    __shared__ int lds[256];
    int ty = blockIdx.y;
    int n = A.n1[ty];
    int* a = A.ofs[ty];
    int* bsum = A.bsum[ty];
    int t = threadIdx.x;
    int base = blockIdx.x * 2048 + t * 8;
    int v[8];
    int run = 0;
#pragma unroll
    for (int j = 0; j < 8; ++j) {
        int idx = base + j;
        int x = (idx < n) ? a[idx] : 0;
        run += x;
        v[j] = run;
    }
    lds[t] = run;
    __syncthreads();
#pragma unroll
    for (int off = 1; off < 256; off <<= 1) {
        int x = (t >= off) ? lds[t - off] : 0;
        __syncthreads();
        lds[t] += x;
        __syncthreads();
    }
    int excl = t ? lds[t - 1] : 0;
#pragma unroll
    for (int j = 0; j < 8; ++j) {
        int idx = base + j;
        if (idx < n) a[idx] = v[j] + excl;
    }
    if (t == 255) bsum[blockIdx.x] = lds[255];
}

__global__ __launch_bounds__(256)
void csr_scan_bsums(CsrArgs A, int nb) {
    __shared__ int lds[256];
    int ty = blockIdx.x;
    int* bsum = A.bsum[ty];
    int t = threadIdx.x;
    int carry = 0;
    for (int base = 0; base < nb; base += 256) {
        int i = base + t;
        int v = (i < nb) ? bsum[i] : 0;
        lds[t] = v;
        __syncthreads();
#pragma unroll
        for (int off = 1; off < 256; off <<= 1) {
            int x = (t >= off) ? lds[t - off] : 0;
            __syncthreads();
            lds[t] += x;
            __syncthreads();
        }
        int excl = t ? lds[t - 1] : 0;
        if (i < nb) bsum[i] = excl + carry;
        carry += lds[255];
        __syncthreads();
    }
}

__global__ __launch_bounds__(256)
void csr_scan_add(CsrArgs A) {
    int ty = blockIdx.y;
    int n = A.n1[ty];
    int* a = A.ofs[ty];
    const int* bsum = A.bsum[ty];
    int* tick = A.tick[ty];
    int i = blockIdx.x * 256 + threadIdx.x;
    if (i < n) {
        int v = a[i] + bsum[i >> 11];
        a[i] = v;
        if (i < n - 1) tick[i] = v;
    }
}

__global__ __launch_bounds__(256)
void csr_fill(CsrArgs A) {
    int ty = blockIdx.y;
    int E = A.E[ty];
    const int* si = A.si[ty];
    const int* di = A.di[ty];
    int* tick = A.tick[ty];
    int* esrc = A.esrc[ty];
    for (int i = blockIdx.x * 256 + threadIdx.x; i < E; i += gridDim.x * 256) {
        int pos = atomicAdd(&tick[di[i]], 1);
        pos = pos < 0 ? 0 : (pos >= E ? E - 1 : pos);
        esrc[pos] = si[i];
    }
}

struct SageAll {
    int bend[3];
    int nd[3];
    int nc[3];
    const float* xdst_f[3];
    float* out[3];
    const float* xsrc_f[3][2];
    const int* ofs[3][2];
    const int* esrc[3][2];
    const bf16* wf[3][2];
    const float* bias[3][2];
    int nsrc[3][2];
    int E[3][2];
};

__global__ __launch_bounds__(256)
void sage_all(SageAll A) {
    int bid = blockIdx.x;
    int g = (bid >= A.bend[0]) + (bid >= A.bend[1]);
    int bloc = bid - (g ? A.bend[g - 1] : 0);
    int lane = threadIdx.x & 63;
    int wave = threadIdx.x >> 6;
    int m = lane & 15;
    int q = lane >> 4;
    int nd = A.nd[g];
    int r0 = bloc * 64 + wave * 16;
    int rl = min(r0 + m, nd - 1);

    bf16x8 a1[4];
    const f32x4* xrow = (const f32x4*)(A.xdst_f[g] + (size_t)rl * 128);
#pragma unroll
    for (int kc = 0; kc < 4; ++kc)
        a1[kc] = pack_bf16x8(xrow[kc * 8 + q * 2], xrow[kc * 8 + q * 2 + 1]);

    float ysum[8][4];
#pragma unroll
    for (int ct = 0; ct < 8; ++ct)
#pragma unroll
        for (int r = 0; r < 4; ++r) ysum[ct][r] = 0.f;

    int nc = A.nc[g];
    for (int c = 0; c < nc; ++c) {
        const int* ofs  = A.ofs[g][c];
        const int* esrc = A.esrc[g][c];
        int nsrc = A.nsrc[g][c];
        int Et   = A.E[g][c];

        int start = ofs[rl];
        int end   = ofs[rl + 1];
        start = start < 0 ? 0 : (start > Et ? Et : start);
        end   = end < start ? start : (end > Et ? Et : end);

        f32x4 aglo[4], aghi[4];
#pragma unroll
        for (int kc = 0; kc < 4; ++kc) {
            aglo[kc] = (f32x4){0.f, 0.f, 0.f, 0.f};
            aghi[kc] = (f32x4){0.f, 0.f, 0.f, 0.f};
        }
        for (int e = start; e < end; ++e) {
            int s = esrc[e];
            s = s < 0 ? 0 : (s >= nsrc ? nsrc - 1 : s);
            accum_src<0>(A.xsrc_f[g][c], nullptr, s, q, aglo, aghi);
        }

        float invc = 1.0f / (float)max(end - start, 1);
        bf16x8 a2[4];
#pragma unroll
        for (int kc = 0; kc < 4; ++kc) {
            bf16x8 t;
#pragma unroll
            for (int j = 0; j < 4; ++j) {
                t[j]     = (__bf16)(aglo[kc][j] * invc);
                t[4 + j] = (__bf16)(aghi[kc][j] * invc);
            }
            a2[kc] = t;
        }

        const bf16x8* wf = (const bf16x8*)A.wf[g][c];
        int fb = q * 16 + m;
        f32x4 acc[8];
#pragma unroll
        for (int ct = 0; ct < 8; ++ct) {
            f32x4 cc = {0.f, 0.f, 0.f, 0.f};
#pragma unroll
            for (int kc = 0; kc < 4; ++kc) {
                bf16x8 bl = wf[(ct * 4 + kc) * 64 + fb];
                bf16x8 br = wf[2048 + (ct * 4 + kc) * 64 + fb];
                cc = __builtin_amdgcn_mfma_f32_16x16x32_bf16(a1[kc], bl, cc, 0, 0, 0);
                cc = __builtin_amdgcn_mfma_f32_16x16x32_bf16(a2[kc], br, cc, 0, 0, 0);
            }
            acc[ct] = cc;
        }

        const float* bias = A.bias[g][c];
        float ss2[4] = {0.f, 0.f, 0.f, 0.f};
#pragma unroll
        for (int ct = 0; ct < 8; ++ct) {
            float bb = bias[ct * 16 + m];
#pragma unroll
            for (int r = 0; r < 4; ++r) {
                float v = acc[ct][r] + bb;
                acc[ct][r] = v;
                ss2[r] += v * v;
            }
        }
#pragma unroll
        for (int off = 1; off < 16; off <<= 1) {
#pragma unroll
            for (int r = 0; r < 4; ++r) ss2[r] += __shfl_xor(ss2[r], off);
        }
        float sc[4];
#pragma unroll
        for (int r = 0; r < 4; ++r) sc[r] = 1.0f / fmaxf(sqrtf(ss2[r]), 1e-12f);
#pragma unroll
        for (int ct = 0; ct < 8; ++ct)
#pragma unroll
            for (int r = 0; r < 4; ++r) ysum[ct][r] += acc[ct][r] * sc[r];
    }

#pragma unroll
    for (int r = 0; r < 4; ++r) {
        int orow = r0 + q * 4 + r;
        if (orow < nd) {
            float* op = A.out[g] + (size_t)orow * 128 + m;
#pragma unroll
            for (int ct = 0; ct < 8; ++ct) op[ct * 16] = ysum[ct][r];
        }
    }
}

extern "C" void kernel_launch(void* const* d_in, const int* in_sizes, int n_in,
                              void* d_out, int out_size, void* d_ws, size_t ws_size,
                              hipStream_t stream) {
    const int D = 128;
    const float* xarr[3] = {(const float*)d_in[0], (const float*)d_in[1],
                            (const float*)d_in[2]};
    int NA = in_sizes[0] / D;
    int NE = in_sizes[1] / D;
    int NF = in_sizes[2] / D;
    int nrow[3] = {NA, NE, NF};

    const int* si[5];
    const int* di[5];
    int Et[5];
    for (int i = 0; i < 5; ++i) {
        si[i] = (const int*)d_in[3 + 2 * i];
        di[i] = (const int*)d_in[4 + 2 * i];
        Et[i] = in_sizes[3 + 2 * i];
    }
    const float *wl[5], *bia[5], *wr[5];
    for (int i = 0; i < 5; ++i) {
        wl[i]  = (const float*)d_in[13 + 3 * i];
        bia[i] = (const float*)d_in[14 + 3 * i];
        wr[i]  = (const float*)d_in[15 + 3 * i];
    }

    float* outp = (float*)d_out;
    float* grp_out[3] = {outp, outp + (size_t)NA * D, outp + (size_t)(NA + NE) * D};

    // EDGE_TYPES: (art->ent), (art->fact), (ent->art), (ent->fact), (fact->ent)
    int xsrc_idx[5] = {0, 0, 1, 1, 2};
    int ndst[5]     = {NE, NF, NA, NF, NE};
    int grp_types[3][2] = {{2, -1}, {0, 4}, {1, 3}};  // article, entity, fact
    int grp_nt[3]  = {1, 2, 2};
    int grp_nd[3]  = {NA, NE, NF};
    int grp_dst[3] = {0, 1, 2};

    size_t wf_bytes = (size_t)5 * 32768 * sizeof(bf16);
    size_t xb_elems = ((size_t)NA + NE + NF) * D;

    // Weight fragments always live at ws base.
    bf16* wfrag = (bf16*)d_ws;
    WConvArgs wa;
    for (int t = 0; t < 5; ++t) {
        wa.w[t * 2]     = wl[t];
        wa.w[t * 2 + 1] = wr[t];
    }
    wa.dst = wfrag;
    convert_w<<<dim3(8, 10), 256, 0, stream>>>(wa);

    // ---------------- PATH A layout attempt (bucket grouping) ----------------
    struct BktLayout {
        size_t tick[5], ovfn[5], bkt[5], ovf[5], xb, end;
    };
    auto layout_bkt = [&](int C, int want_xb, BktLayout& L) -> bool {
        size_t p = (wf_bytes + 63) & ~(size_t)63;
        for (int t = 0; t < 5; ++t) {
            L.tick[t] = p; p += (size_t)ndst[t] * 4;
            L.ovfn[t] = p; p += 64;
            L.bkt[t] = p; p += (size_t)ndst[t] * C * 4;
            p = (p + 15) & ~(size_t)15;
            L.ovf[t] = p; p += (size_t)Et[t] * 8;
            p = (p + 15) & ~(size_t)15;
        }
        L.xb = p;
        if (want_xb) p += xb_elems * sizeof(bf16);
        L.end = p;
        return p <= ws_size;
    };

    BktLayout L;
    int C = 0, use_xb = 0;
    if (layout_bkt(16, 1, L))      { C = 16; use_xb = 1; }
    else if (layout_bkt(8, 1, L))  { C = 8;  use_xb = 1; }
    else if (layout_bkt(16, 0, L)) { C = 16; use_xb = 0; }
    else if (layout_bkt(8, 0, L))  { C = 8;  use_xb = 0; }

    if (C > 0) {
        bf16* xb = (bf16*)((char*)d_ws + L.xb);
        bf16* xb_arr[3] = {xb, xb + (size_t)NA * D, xb + ((size_t)NA + NE) * D};
        if (use_xb) {
            XConvArgs xa;
            for (int a = 0; a < 3; ++a) {
                xa.src[a] = xarr[a];
                xa.dst[a] = xb_arr[a];
                xa.n8[a]  = (long long)nrow[a] * 16;
            }
            convert_x<<<dim3(2048, 3), 256, 0, stream>>>(xa);
        }

        FillArgs fa = {};
        int max_nd = 0;
        for (int t = 0; t < 5; ++t) {
            fa.si[t] = si[t];
            fa.di[t] = di[t];
            fa.tick[t]   = (int*)((char*)d_ws + L.tick[t]);
            fa.bucket[t] = (int*)((char*)d_ws + L.bkt[t]);
            fa.ovf[t]    = (int2*)((char*)d_ws + L.ovf[t]);
            fa.ovfn[t]   = (int*)((char*)d_ws + L.ovfn[t]);
            fa.E[t] = Et[t];
            fa.nd[t] = ndst[t];
            if (ndst[t] > max_nd) max_nd = ndst[t];
        }
        fa.C = C;
        bkt_zero<<<dim3((max_nd + 255) / 256, 5), 256, 0, stream>>>(fa);
        bkt_fill<<<dim3(1024, 5), 256, 0, stream>>>(fa);

        SageB sb = {};
        int cum = 0;
        for (int g = 0; g < 3; ++g) {
            sb.nd[g] = grp_nd[g];
            sb.nc[g] = grp_nt[g];
            sb.xdst_f[g] = xarr[grp_dst[g]];
            sb.xdst_b[g] = xb_arr[grp_dst[g]];
            sb.out[g] = grp_out[g];
            for (int c = 0; c < grp_nt[g]; ++c) {
                int t = grp_types[g][c];
                sb.xsrc_f[g][c] = xarr[xsrc_idx[t]];
                sb.xsrc_b[g][c] = xb_arr[xsrc_idx[t]];
                sb.tick[g][c]   = fa.tick[t];
                sb.bucket[g][c] = fa.bucket[t];
                sb.ovf[g][c]    = fa.ovf[t];
                sb.ovfn[g][c]   = fa.ovfn[t];
                sb.wf[g][c]     = wfrag + (size_t)t * 32768;
                sb.bias[g][c]   = bia[t];
                sb.nsrc[g][c]   = nrow[xsrc_idx[t]];
                sb.ovfcap[g][c] = Et[t];
            }
            cum += (grp_nd[g] + 63) / 64;
            sb.bend[g] = cum;
        }
        if (C == 16 && use_xb)       sage_bkt<16, 1><<<cum, 256, 0, stream>>>(sb);
        else if (C == 8 && use_xb)   sage_bkt<8, 1><<<cum, 256, 0, stream>>>(sb);
        else if (C == 16)            sage_bkt<16, 0><<<cum, 256, 0, stream>>>(sb);
        else                         sage_bkt<8, 0><<<cum, 256, 0, stream>>>(sb);
        return;
    }

    // ---------------- PATH B fallback (round-5 CSR, proven fit) ----------------
    size_t csr_all_ints = 0;
    for (int t = 0; t < 5; ++t)
        csr_all_ints += (size_t)(ndst[t] + 1) + ndst[t] + Et[t] + 128;
    size_t off_csr = (wf_bytes + 15) & ~(size_t)15;
    int mode_lean = (off_csr + csr_all_ints * 4) <= ws_size;

    int* type_ofs[5];
    int* type_esrc[5];
    auto run_csr = [&](const int* types, int nt, int* base) {
        CsrArgs ca = {};
        int* p = base;
        int max_n1 = 0;
        for (int k = 0; k < nt; ++k) {
            int t = types[k];
            int nd = ndst[t], n1 = nd + 1, E = Et[t];
            ca.si[k] = si[t];
            ca.di[k] = di[t];
            ca.ofs[k]  = p; p += n1;
            ca.tick[k] = p; p += nd;
            ca.esrc[k] = p; p += E;
            ca.bsum[k] = p; p += 128;
            ca.E[k] = E;
            ca.n1[k] = n1;
            if (n1 > max_n1) max_n1 = n1;
            type_ofs[t]  = ca.ofs[k];
            type_esrc[t] = ca.esrc[k];
        }
        int blk = (max_n1 + 255) / 256;
        int nb  = (max_n1 + 2047) / 2048;
        csr_zero<<<dim3(blk, nt), 256, 0, stream>>>(ca);
        csr_hist<<<dim3(1024, nt), 256, 0, stream>>>(ca);
        csr_scan_blocks<<<dim3(nb, nt), 256, 0, stream>>>(ca);
        csr_scan_bsums<<<dim3(nt), 256, 0, stream>>>(ca, nb);
        csr_scan_add<<<dim3(blk, nt), 256, 0, stream>>>(ca);
        csr_fill<<<dim3(1024, nt), 256, 0, stream>>>(ca);
    };

    auto fill_group = [&](SageAll& sa, int slot, int g) {
        sa.nd[slot] = grp_nd[g];
        sa.nc[slot] = grp_nt[g];
        sa.xdst_f[slot] = xarr[grp_dst[g]];
        sa.out[slot] = grp_out[g];
        for (int c = 0; c < grp_nt[g]; ++c) {
            int t = grp_types[g][c];
            sa.xsrc_f[slot][c] = xarr[xsrc_idx[t]];
            sa.ofs[slot][c]  = type_ofs[t];
            sa.esrc[slot][c] = type_esrc[t];
            sa.wf[slot][c]   = wfrag + (size_t)t * 32768;
            sa.bias[slot][c] = bia[t];
            sa.nsrc[slot][c] = nrow[xsrc_idx[t]];
            sa.E[slot][c]    = Et[t];
        }
    };

    int* csr_base = (int*)((char*)d_ws + off_csr);
    if (mode_lean) {
        int all_types[5] = {0, 1, 2, 3, 4};
        run_csr(all_types, 5, csr_base);
        SageAll sa = {};
        int cum = 0;
        for (int g = 0; g < 3; ++g) {
            fill_group(sa, g, g);
            cum += (grp_nd[g] + 63) / 64;
            sa.bend[g] = cum;
        }
        sage_all<<<cum, 256, 0, stream>>>(sa);
    } else {
        for (int g = 0; g < 3; ++g) {
            run_csr(grp_types[g], grp_nt[g], csr_base);
            SageAll sa = {};
            fill_group(sa, 0, g);
            int nb = (grp_nd[g] + 63) / 64;
            sa.bend[0] = nb; sa.bend[1] = nb; sa.bend[2] = nb;
            sage_all<<<nb, 256, 0, stream>>>(sa);
        }
    }
}